// Round 14
// baseline (426.360 us; speedup 1.0000x reference)
//
#include <hip/hip_runtime.h>
#include <hip/hip_bf16.h>
#include <stdint.h>

#define BDIM 1024
#define SDIM 256
#define VDIM 32000
#define EDIM 300
#define HDIM 256
#define ENCD 768
#define G4H  1024
#define KXI  1344   // 300 + 768 + 256 = 1324 padded to 42*32

typedef short bf16x8 __attribute__((ext_vector_type(8)));
typedef float f32x4  __attribute__((ext_vector_type(4)));

typedef __attribute__((address_space(3))) void       lds_void;
typedef const __attribute__((address_space(1))) void gbl_void;

static __device__ __forceinline__ unsigned short f2bf(float f) {
  __hip_bfloat16 b = __float2bfloat16(f);   // RNE
  return *reinterpret_cast<unsigned short*>(&b);
}
static __device__ __forceinline__ unsigned pk2(float x, float y) {
  float2 f; f.x = x; f.y = y;
  __hip_bfloat162 h = __float22bfloat162_rn(f);   // packed RNE (v_cvt_pk_bf16_f32)
  return *reinterpret_cast<unsigned*>(&h);
}
static __device__ __forceinline__ float bf2f(unsigned short u) {
  union { unsigned u; float f; } v; v.u = ((unsigned)u) << 16; return v.f;
}
static __device__ __forceinline__ float sigf(float x) {
  return 1.0f / (1.0f + __expf(-x));
}
static __device__ __forceinline__ float tanh_fast(float x) {
  return 1.0f - 2.0f / (__expf(2.0f * x) + 1.0f);   // saturates correctly at +-inf
}
// swizzled byte offset inside a 32-row encT tile: row stride 1536B, XOR 16B chunks by (row&7)
static __device__ __forceinline__ int swz_off(int row, int kbyte) {
  return row * 1536 + (kbyte ^ ((row & 7) << 4));
}
// raw barrier that does NOT drain vmcnt (keeps gl_lds streams in flight);
// lgkmcnt(0) orders LDS ops; sched_barrier pins (rule #18).
static __device__ __forceinline__ void lds_barrier() {
  asm volatile("s_waitcnt lgkmcnt(0)" ::: "memory");
  __builtin_amdgcn_sched_barrier(0);
  __builtin_amdgcn_s_barrier();
  __builtin_amdgcn_sched_barrier(0);
}

// ---------------- prep: bf16 conversions + xi emb/h/pad sections ----------------
// w_e packed in MFMA-FRAGMENT ORDER: entry f (16B = 8 bf16):
//   lane = f & 63; n = (f>>6)&1; kt = (f>>7)%24; w = (f>>7)/24
//   j = 32w + 16n + (lane&15); k = 32kt + (lane>>4)*8 + e
__global__ void k_prep(const float* __restrict__ attn_w, const float* __restrict__ w_ih,
                       const float* __restrict__ w_hh, const float* __restrict__ out_w,
                       const float* __restrict__ h, const int* __restrict__ x,
                       const float* __restrict__ emb,
                       unsigned short* __restrict__ w_e_frag, unsigned short* __restrict__ w_h_b,
                       unsigned short* __restrict__ h_b,
                       unsigned short* __restrict__ Wb, unsigned short* __restrict__ outw_b,
                       unsigned short* __restrict__ xi_b) {
  const long NWE = (long)HDIM * ENCD;       // 196608
  const long NW1 = (long)HDIM * HDIM;       // 65536  (w_h_b)
  const long NHB = (long)BDIM * HDIM;       // 262144 (h_b)
  const long NWB = (long)G4H * KXI;         // 1376256
  const long NOW = (long)VDIM * HDIM;       // 8192000
  const long NEM = (long)BDIM * EDIM;       // 307200 (xi emb section)
  const long NH2 = (long)BDIM * HDIM;       // 262144 (xi h section)
  const long NPD = (long)BDIM * (KXI - (EDIM + ENCD + HDIM));  // 20480 (xi pad)
  const long total = NWE + NW1 + NHB + NWB + NOW + NEM + NH2 + NPD;
  for (long idx = blockIdx.x * 256L + threadIdx.x; idx < total; idx += gridDim.x * 256L) {
    long i = idx;
    if (i < NWE) {
      int e    = (int)(i & 7);
      int f    = (int)(i >> 3);
      int lane = f & 63;
      int n    = (f >> 6) & 1;
      int r2   = f >> 7;          // w*24 + kt
      int kt   = r2 % 24;
      int w    = r2 / 24;
      int j    = 32 * w + 16 * n + (lane & 15);
      int k    = 32 * kt + (lane >> 4) * 8 + e;
      w_e_frag[i] = f2bf(attn_w[j * (4 * HDIM) + HDIM + k]);
    } else if ((i -= NWE) < NW1) {
      int j = (int)(i / HDIM), k = (int)(i % HDIM);
      w_h_b[i] = f2bf(attn_w[j * (4 * HDIM) + k]);
    } else if ((i -= NW1) < NHB) {
      h_b[i] = f2bf(h[i]);
    } else if ((i -= NHB) < NWB) {
      int g = (int)(i / KXI), k = (int)(i % KXI);
      float v = 0.f;
      if (k < EDIM + ENCD) v = w_ih[(long)g * (EDIM + ENCD) + k];
      else if (k < EDIM + ENCD + HDIM) v = w_hh[(long)g * HDIM + (k - (EDIM + ENCD))];
      Wb[i] = f2bf(v);
    } else if ((i -= NWB) < NOW) {
      outw_b[i] = f2bf(out_w[i]);
    } else if ((i -= NOW) < NEM) {
      int b = (int)(i / EDIM), cc = (int)(i % EDIM);
      xi_b[(long)b * KXI + cc] = f2bf(emb[(long)x[b] * EDIM + cc]);
    } else if ((i -= NEM) < NH2) {
      int b = (int)(i / HDIM), j = (int)(i % HDIM);
      xi_b[(long)b * KXI + EDIM + ENCD + j] = f2bf(h[(long)b * HDIM + j]);
    } else {
      i -= NH2;
      const int PADW = KXI - (EDIM + ENCD + HDIM);
      int b = (int)(i / PADW), p = (int)(i % PADW);
      xi_b[(long)b * KXI + EDIM + ENCD + HDIM + p] = 0;
    }
  }
}

// ---------------- persistent fused energy GEMM + tanh + scores + exp + context + xi ----------------
// grid=256 (1 WG/CU), 32 tiles/WG (4 whole b-rows). LDS: 96KB fp32 stage buffer
// (filled by global_load_lds, fire-and-forget, ZERO registers) + 48KB swizzled
// bf16 encT + accumulators. Per tile: syncthreads (drains gl_lds of this tile)
// -> LDS->LDS convert -> lds_barrier -> issue gl_lds(t+1) (streams under all
// remaining phases) -> K-loop (B rolling 4-deep from L2 frag table) -> scores
// -> softmax (accumulate denom) -> context (accumulate in LDS; on st==7 write
// normalized ctx directly to xi_b as bf16). No register-resident staging data.
__launch_bounds__(512, 1)
__global__ void k_energy_ctx(const float* __restrict__ enc, const unsigned short* __restrict__ w_e_frag,
                             const float* __restrict__ hwb, const float* __restrict__ v_w,
                             unsigned short* __restrict__ xi_b) {
  const int t = threadIdx.x;
  const int lane = t & 63;
  const int w = t >> 6;          // wave 0..7, owns j in [32w, 32w+32)
  const int li = lane & 15;
  const int lg = lane >> 4;
  const int jw = 32 * w;

  __shared__ __align__(16) float stageF[32 * ENCD];          // 96KB fp32 staging
  __shared__ __align__(16) unsigned short encT[32 * ENCD];   // 48KB bf16, swizzled
  __shared__ float scores_lds[8 * 32];
  __shared__ float p_lds[32];
  __shared__ float ctxAcc[ENCD];
  __shared__ float hwb_lds[4 * HDIM];
  __shared__ float denAcc;

  const int NT = 32;
  const int tile0 = blockIdx.x * NT;    // 256 WGs x 32 tiles = 8192
  const int b0 = tile0 >> 3;            // 4 whole b rows per WG

  // ---- prologue: issue gl_lds for tile0 (no registers consumed) ----
  {
    const float* src = enc + (long)tile0 * 32 * ENCD;
#pragma unroll
    for (int u = 0; u < 12; ++u) {
      const float* s = src + (u * 512 + t) * 4;
      char* d = (char*)stageF + (u * 512 + (w << 6)) * 16;   // wave-uniform base; HW adds lane*16
      __builtin_amdgcn_global_load_lds((gbl_void*)s, (lds_void*)d, 16, 0, 0);
    }
  }
  hwb_lds[t]       = hwb[b0 * HDIM + t];
  hwb_lds[t + 512] = hwb[b0 * HDIM + t + 512];
  const float vw0 = v_w[jw + li];
  const float vw1 = v_w[jw + 16 + li];
  const unsigned short* fragW = w_e_frag + ((long)w * 3072 + lane) * 8;

  // ---- persistent tile loop ----
  for (int it = 0; it < NT; ++it) {
    const int tile = tile0 + it;
    const int b = tile >> 3, st = tile & 7;
    const bool more = (it + 1 < NT);

    __syncthreads();   // drains vmcnt: gl_lds(tile) landed; prev tile's LDS reads done

    if (st == 0) {
      if (t < 384) { ctxAcc[2 * t] = 0.f; ctxAcc[2 * t + 1] = 0.f; }
      if (t == 0) denAcc = 0.f;
    }

    // 1) convert stageF (fp32, linear) -> encT (bf16, swizzled); pure LDS<->LDS
#pragma unroll
    for (int u = 0; u < 12; ++u) {
      const int s = u * 512 + t;
      float4 v = *(const float4*)&stageF[4 * s];
      const int flat = 4 * s;
      const int row = flat / ENCD;
      const int col = flat - row * ENCD;
      uint2 pk;
      pk.x = pk2(v.x, v.y);
      pk.y = pk2(v.z, v.w);
      *(uint2*)((char*)encT + swz_off(row, col * 2)) = pk;
    }
    lds_barrier();   // encT ready for all waves; stageF free for refill

    // 2) issue gl_lds for tile+1 — streams under K-loop/scores/softmax/context
    if (more) {
      const float* src = enc + (long)(tile + 1) * 32 * ENCD;
#pragma unroll
      for (int u = 0; u < 12; ++u) {
        const float* s = src + (u * 512 + t) * 4;
        char* d = (char*)stageF + (u * 512 + (w << 6)) * 16;
        __builtin_amdgcn_global_load_lds((gbl_void*)s, (lds_void*)d, 16, 0, 0);
      }
    }

    const float hw0 = hwb_lds[(b - b0) * HDIM + jw + li];
    const float hw1 = hwb_lds[(b - b0) * HDIM + jw + 16 + li];

    // 3) K-loop: A from encT (LDS), B rolling 4-deep from L2-resident frag table
    f32x4 acc[2][2];
#pragma unroll
    for (int m = 0; m < 2; m++)
#pragma unroll
      for (int n = 0; n < 2; n++) { f32x4 z = {0.f, 0.f, 0.f, 0.f}; acc[m][n] = z; }

    bf16x8 bfr[4][2];
#pragma unroll
    for (int p = 0; p < 4; ++p)
#pragma unroll
      for (int n = 0; n < 2; ++n)
        bfr[p][n] = *(const bf16x8*)(fragW + ((p * 2 + n) * 64) * 8);

#pragma unroll
    for (int kt = 0; kt < 24; ++kt) {
      const int kb = kt & 3;
      bf16x8 a[2];
#pragma unroll
      for (int m = 0; m < 2; m++)
        a[m] = *(const bf16x8*)((const char*)encT + swz_off(16 * m + li, (kt * 32 + lg * 8) * 2));
#pragma unroll
      for (int m = 0; m < 2; m++)
#pragma unroll
        for (int n = 0; n < 2; n++)
          acc[m][n] = __builtin_amdgcn_mfma_f32_16x16x32_bf16(a[m], bfr[kb][n], acc[m][n], 0, 0, 0);
      if (kt + 4 < 24) {
#pragma unroll
        for (int n = 0; n < 2; ++n)
          bfr[kb][n] = *(const bf16x8*)(fragW + (((kt + 4) * 2 + n) * 64) * 8);
      }
    }

    // 4) scores: tanh -> *v_w -> j-reduce
    float val[2][4];
#pragma unroll
    for (int m = 0; m < 2; m++)
#pragma unroll
      for (int r = 0; r < 4; r++) {
        float v0 = tanh_fast(acc[m][0][r] + hw0) * vw0 + tanh_fast(acc[m][1][r] + hw1) * vw1;
        v0 += __shfl_xor(v0, 1);
        v0 += __shfl_xor(v0, 2);
        v0 += __shfl_xor(v0, 4);
        v0 += __shfl_xor(v0, 8);
        val[m][r] = v0;
      }
    if (li < 4) {
      scores_lds[w * 32 + 4 * lg + li]      = val[0][li];
      scores_lds[w * 32 + 16 + 4 * lg + li] = val[1][li];
    }
    lds_barrier();   // BAR1

    // 5) softmax over s (unnormalized exp safe: |score| <= sum|v_w| ~ 4); accumulate denom
    if (t < 32) {
      float sc = 0.f;
#pragma unroll
      for (int ww = 0; ww < 8; ++ww) sc += scores_lds[ww * 32 + t];
      float p = __expf(sc);
      p_lds[t] = p;
      float dsum = p;
      dsum += __shfl_xor(dsum, 1);
      dsum += __shfl_xor(dsum, 2);
      dsum += __shfl_xor(dsum, 4);
      dsum += __shfl_xor(dsum, 8);
      dsum += __shfl_xor(dsum, 16);
      if (t == 0) denAcc += dsum;
    }
    lds_barrier();   // BAR2 (denAcc visible)

    // 6) context accumulate from LDS tile; on st==7 write normalized ctx to xi_b
    if (t < 384) {
      float cx = 0.f, cy = 0.f;
#pragma unroll
      for (int s = 0; s < 32; ++s) {
        float p = p_lds[s];
        unsigned u = *(const unsigned*)((const char*)encT + swz_off(s, 4 * t));
        cx += p * bf2f((unsigned short)(u & 0xffffu));
        cy += p * bf2f((unsigned short)(u >> 16));
      }
      cx += ctxAcc[2 * t];
      cy += ctxAcc[2 * t + 1];
      if (st == 7) {
        const float inv = 1.0f / denAcc;
        unsigned pk = (unsigned)f2bf(cx * inv) | ((unsigned)f2bf(cy * inv) << 16);
        *(unsigned*)&xi_b[(long)b * KXI + EDIM + 2 * t] = pk;
      } else {
        ctxAcc[2 * t]     = cx;
        ctxAcc[2 * t + 1] = cy;
      }
    }
    // next iteration's __syncthreads orders these LDS reads vs next convert
  }
}

// ---------------- generic 128x128 bf16 GEMM, C = A * Bt^T + bias ----------------
__launch_bounds__(256)
__global__ void k_gemm_bt(const unsigned short* __restrict__ A, const unsigned short* __restrict__ Bt,
                          const float* __restrict__ bias1, const float* __restrict__ bias2,
                          float* __restrict__ out, int N, int K, int MTILES) {
  int bx = blockIdx.x;
  int mt = bx % MTILES, nt = bx / MTILES;
  int row0 = mt * 128, col0 = nt * 128;
  int t = threadIdx.x, lane = t & 63, w = t >> 6;
  int li = lane & 15, lg = lane >> 4;
  int wr = (w >> 1) * 64, wc = (w & 1) * 64;
  __shared__ __align__(16) unsigned short As[2][128 * 32];
  __shared__ __align__(16) unsigned short Bs[2][128 * 32];
  f32x4 acc[4][4];
#pragma unroll
  for (int m = 0; m < 4; m++)
#pragma unroll
    for (int n = 0; n < 4; n++) { f32x4 z = {0.f, 0.f, 0.f, 0.f}; acc[m][n] = z; }

  auto stage = [&](int buf, int k0) {
#pragma unroll
    for (int rep = 0; rep < 2; ++rep) {
      int slot = t + rep * 256;
      int r = slot >> 2, sg = slot & 3;
      uint4 va = *(const uint4*)(A + (long)(row0 + r) * K + k0 + sg * 8);
      uint4 vb = *(const uint4*)(Bt + (long)(col0 + r) * K + k0 + sg * 8);
      *(uint4*)&As[buf][r * 32 + sg * 8] = va;
      *(uint4*)&Bs[buf][r * 32 + sg * 8] = vb;
    }
  };

  stage(0, 0);
  __syncthreads();
  const int nk = K / 32;
  for (int kt = 0; kt < nk; ++kt) {
    if (kt + 1 < nk) stage((kt + 1) & 1, (kt + 1) * 32);
    int cb = kt & 1;
    bf16x8 a[4], bb[4];
#pragma unroll
    for (int m = 0; m < 4; m++) a[m] = *(const bf16x8*)&As[cb][(wr + 16 * m + li) * 32 + lg * 8];
#pragma unroll
    for (int n = 0; n < 4; n++) bb[n] = *(const bf16x8*)&Bs[cb][(wc + 16 * n + li) * 32 + lg * 8];
#pragma unroll
    for (int m = 0; m < 4; m++)
#pragma unroll
      for (int n = 0; n < 4; n++)
        acc[m][n] = __builtin_amdgcn_mfma_f32_16x16x32_bf16(a[m], bb[n], acc[m][n], 0, 0, 0);
    __syncthreads();
  }

#pragma unroll
  for (int n = 0; n < 4; n++) {
    int col = col0 + wc + 16 * n + li;
    float bs = bias1[col];
    if (bias2) bs += bias2[col];
#pragma unroll
    for (int m = 0; m < 4; m++) {
      int rb = row0 + wr + 16 * m + lg * 4;
#pragma unroll
      for (int r = 0; r < 4; r++)
        out[(long)(rb + r) * N + col] = acc[m][n][r] + bs;
    }
  }
}

// ---------------- LSTM pointwise ----------------
__global__ void k_lstm(const float* __restrict__ gates, const float* __restrict__ c,
                       float* __restrict__ h2, float* __restrict__ c2,
                       unsigned short* __restrict__ h2b) {
  int b = blockIdx.x, j = threadIdx.x;
  const float* g = gates + (long)b * G4H;
  float ig = sigf(g[j]);
  float fg = sigf(g[HDIM + j]);
  float gg = tanh_fast(g[2 * HDIM + j]);
  float og = sigf(g[3 * HDIM + j]);
  float cv = c[b * HDIM + j];
  float c2v = fg * cv + ig * gg;
  float h2v = og * tanh_fast(c2v);
  c2[b * HDIM + j] = c2v;
  h2[b * HDIM + j] = h2v;
  h2b[b * HDIM + j] = f2bf(h2v);
}

extern "C" void kernel_launch(void* const* d_in, const int* in_sizes, int n_in,
                              void* d_out, int out_size, void* d_ws, size_t ws_size,
                              hipStream_t stream) {
  const int*   x      = (const int*)d_in[0];
  const float* h      = (const float*)d_in[1];
  const float* c      = (const float*)d_in[2];
  const float* enc    = (const float*)d_in[3];
  const float* emb    = (const float*)d_in[4];
  const float* attn_w = (const float*)d_in[5];
  const float* attn_b = (const float*)d_in[6];
  const float* v_w    = (const float*)d_in[7];
  const float* w_ih   = (const float*)d_in[8];
  const float* w_hh   = (const float*)d_in[9];
  const float* b_ih   = (const float*)d_in[10];
  const float* b_hh   = (const float*)d_in[11];
  const float* out_w  = (const float*)d_in[12];
  const float* out_b  = (const float*)d_in[13];
  float* out = (float*)d_out;

  // workspace layout (bytes)
  char* ws = (char*)d_ws;
  float* hwb             = (float*)(ws + 0);                 // 1,048,576
  unsigned short* w_e_fr = (unsigned short*)(ws + 1048576);  //   393,216
  unsigned short* w_h_b  = (unsigned short*)(ws + 1441792);  //   131,072
  unsigned short* h_b    = (unsigned short*)(ws + 1572864);  //   524,288
  unsigned short* Wb     = (unsigned short*)(ws + 2097152);  // 2,752,512
  unsigned short* xi_b   = (unsigned short*)(ws + 4849664);  // 2,752,512
  float* gates           = (float*)(ws + 7602176);           // 4,194,304
  unsigned short* h2b    = (unsigned short*)(ws + 11796480); //   524,288
  unsigned short* outw_b = (unsigned short*)(ws + 12320768); // 16,384,000 -> end 28,704,768
  if (ws_size < 28704768u) return;

  k_prep<<<2048, 256, 0, stream>>>(attn_w, w_ih, w_hh, out_w, h, x, emb,
                                   w_e_fr, w_h_b, h_b, Wb, outw_b, xi_b);
  k_gemm_bt<<<16, 256, 0, stream>>>(h_b, w_h_b, attn_b, nullptr, hwb, HDIM, HDIM, 8);
  k_energy_ctx<<<256, 512, 0, stream>>>(enc, w_e_fr, hwb, v_w, xi_b);
  k_gemm_bt<<<64, 256, 0, stream>>>(xi_b, Wb, b_ih, b_hh, gates, G4H, KXI, 8);
  k_lstm<<<1024, 256, 0, stream>>>(gates, c, out + (long)BDIM * VDIM,
                                   out + (long)BDIM * VDIM + (long)BDIM * HDIM, h2b);
  k_gemm_bt<<<2000, 256, 0, stream>>>(h2b, outw_b, out_b, nullptr, out, VDIM, HDIM, 8);
}